// Round 1
// baseline (675.131 us; speedup 1.0000x reference)
//
#include <hip/hip_runtime.h>

#define N_NODES 100000
#define N_EDGES 3200000
#define D_FEAT  512
#define HIDDEN  16
#define NCLS    6

// ---------- helpers ----------

// edge_index may arrive as int32 (JAX x64 disabled) or int64 (x64 enabled).
// flag==1 means int64 layout (view as pairs of i32, low word first, little-endian).
__device__ __forceinline__ int eidx(const int* __restrict__ ei, int is64, int pos) {
    return is64 ? ei[2 * (long long)pos] : ei[pos];
}

// Detect int64 layout: sample 64 odd 32-bit words; if ALL are zero, the buffer
// is int64 (high halves of values < 2^31). For int32 data these words are edge
// indices, nonzero with prob ~1 - 1e-5 each.
__global__ void k_detect(const int* __restrict__ ei, int* __restrict__ flag) {
    int v = ei[2 * threadIdx.x + 1];
    unsigned long long b = __ballot(v != 0);
    if (threadIdx.x == 0) flag[0] = (b == 0ULL) ? 1 : 0;
}

// ---------- degree / norm ----------

__global__ void k_initdeg(float* __restrict__ deg) {
    int i = blockIdx.x * 256 + threadIdx.x;
    if (i < N_NODES) deg[i] = 1.0f;   // self-loop weight 1
}

__global__ void k_degacc(const int* __restrict__ ei, const float* __restrict__ w,
                         const int* __restrict__ flag, float* __restrict__ deg) {
    int e = blockIdx.x * 256 + threadIdx.x;
    if (e >= N_EDGES) return;
    int is64 = flag[0];
    int c = eidx(ei, is64, N_EDGES + e);
    atomicAdd(&deg[c], w[e]);
}

__global__ void k_dinv(float* __restrict__ deg) {
    int i = blockIdx.x * 256 + threadIdx.x;
    if (i < N_NODES) {
        float d = deg[i];
        deg[i] = (d > 0.0f) ? rsqrtf(d) : 0.0f;
    }
}

// ---------- layer 1 transform: h1 = x @ W1 ----------

__global__ __launch_bounds__(256)
void k_gemm1(const float* __restrict__ x, const float* __restrict__ W1g,
             float* __restrict__ h1) {
    __shared__ float w1s[D_FEAT * HIDDEN];   // 32 KB
    for (int p = threadIdx.x; p < D_FEAT * HIDDEN; p += 256) w1s[p] = W1g[p];
    __syncthreads();
    const int total = N_NODES * HIDDEN;
    for (int t = blockIdx.x * 256 + threadIdx.x; t < total; t += gridDim.x * 256) {
        int i = t >> 4, j = t & 15;
        const float4* xr = (const float4*)(x + (size_t)i * D_FEAT);
        float acc = 0.0f;
#pragma unroll 4
        for (int k4 = 0; k4 < D_FEAT / 4; ++k4) {
            float4 xv = xr[k4];
            int kb = (k4 << 6) + j;
            acc = fmaf(xv.x, w1s[kb],      acc);
            acc = fmaf(xv.y, w1s[kb + 16], acc);
            acc = fmaf(xv.z, w1s[kb + 32], acc);
            acc = fmaf(xv.w, w1s[kb + 48], acc);
        }
        h1[t] = acc;
    }
}

// ---------- layer 1 edge scatter: agg1[col] += norm * h1[row] ----------

__global__ __launch_bounds__(256)
void k_scatter1(const int* __restrict__ ei, const float* __restrict__ w,
                const int* __restrict__ flag, const float* __restrict__ dinv,
                const float* __restrict__ h1, float* __restrict__ agg1) {
    int t = blockIdx.x * 256 + threadIdx.x;           // E*16 = 51.2M threads
    if (t >= N_EDGES * HIDDEN) return;
    int e = t >> 4, j = t & 15;
    int is64 = flag[0];
    int r = eidx(ei, is64, e);
    int c = eidx(ei, is64, N_EDGES + e);
    float nrm = dinv[r] * w[e] * dinv[c];
    atomicAdd(&agg1[(size_t)c * HIDDEN + j], nrm * h1[(size_t)r * HIDDEN + j]);
}

// ---------- finish layer 1 (self-loop + bias) and layer 2 transform ----------

__global__ void k_fin1_gemm2(const float* __restrict__ b1, const float* __restrict__ W2,
                             const float* __restrict__ dinv, const float* __restrict__ h1,
                             float* __restrict__ x1, float* __restrict__ h2) {
    int i = blockIdx.x * 256 + threadIdx.x;
    if (i >= N_NODES) return;
    float d2 = dinv[i] * dinv[i];
    float v[HIDDEN];
#pragma unroll
    for (int k = 0; k < HIDDEN; ++k)
        v[k] = x1[(size_t)i * HIDDEN + k] + d2 * h1[(size_t)i * HIDDEN + k] + b1[k];
#pragma unroll
    for (int k = 0; k < HIDDEN; ++k)
        x1[(size_t)i * HIDDEN + k] = v[k];
#pragma unroll
    for (int j = 0; j < NCLS; ++j) {
        float a = 0.0f;
#pragma unroll
        for (int k = 0; k < HIDDEN; ++k) a = fmaf(v[k], W2[k * NCLS + j], a);
        h2[(size_t)i * NCLS + j] = a;
    }
}

// ---------- layer 2 edge scatter ----------

__global__ __launch_bounds__(256)
void k_scatter2(const int* __restrict__ ei, const float* __restrict__ w,
                const int* __restrict__ flag, const float* __restrict__ dinv,
                const float* __restrict__ h2, float* __restrict__ agg2) {
    int t = blockIdx.x * 256 + threadIdx.x;           // E*6 = 19.2M threads
    if (t >= N_EDGES * NCLS) return;
    int e = t / NCLS, j = t - e * NCLS;
    int is64 = flag[0];
    int r = eidx(ei, is64, e);
    int c = eidx(ei, is64, N_EDGES + e);
    float nrm = dinv[r] * w[e] * dinv[c];
    atomicAdd(&agg2[(size_t)c * NCLS + j], nrm * h2[(size_t)r * NCLS + j]);
}

// ---------- finish layer 2 + log_softmax ----------

__global__ void k_final(const float* __restrict__ agg2, const float* __restrict__ h2,
                        const float* __restrict__ dinv, const float* __restrict__ b2,
                        float* __restrict__ out) {
    int i = blockIdx.x * 256 + threadIdx.x;
    if (i >= N_NODES) return;
    float d2 = dinv[i] * dinv[i];
    float v[NCLS];
    float m = -1e30f;
#pragma unroll
    for (int j = 0; j < NCLS; ++j) {
        v[j] = agg2[(size_t)i * NCLS + j] + d2 * h2[(size_t)i * NCLS + j] + b2[j];
        m = fmaxf(m, v[j]);
    }
    float s = 0.0f;
#pragma unroll
    for (int j = 0; j < NCLS; ++j) s += __expf(v[j] - m);
    float l = __logf(s);
#pragma unroll
    for (int j = 0; j < NCLS; ++j) out[(size_t)i * NCLS + j] = v[j] - m - l;
}

// ---------- launch ----------

extern "C" void kernel_launch(void* const* d_in, const int* in_sizes, int n_in,
                              void* d_out, int out_size, void* d_ws, size_t ws_size,
                              hipStream_t stream) {
    const float* x  = (const float*)d_in[0];
    const float* W1 = (const float*)d_in[1];
    const float* b1 = (const float*)d_in[2];
    const float* W2 = (const float*)d_in[3];
    const float* b2 = (const float*)d_in[4];
    const float* ew = (const float*)d_in[5];
    const int*   ei = (const int*)d_in[6];

    float* out = (float*)d_out;
    float* lsm = out;                                  // [N, 6]
    float* x1  = out + (size_t)N_NODES * NCLS;         // [N, 16], accumulates agg1

    float* W    = (float*)d_ws;
    int*   flag = (int*)d_ws;                          // 1 int
    float* deg  = W + 1024;                            // N, becomes dinv in place
    float* h1   = W + 1024 + 100352;                   // N*16
    float* h2   = h1 + (size_t)N_NODES * HIDDEN;       // N*6
    float* agg2 = h2 + (size_t)N_NODES * NCLS;         // N*6

    hipMemsetAsync(x1,   0, (size_t)N_NODES * HIDDEN * sizeof(float), stream);
    hipMemsetAsync(agg2, 0, (size_t)N_NODES * NCLS   * sizeof(float), stream);

    k_detect<<<1, 64, 0, stream>>>(ei, flag);
    k_initdeg<<<(N_NODES + 255) / 256, 256, 0, stream>>>(deg);
    k_degacc<<<(N_EDGES + 255) / 256, 256, 0, stream>>>(ei, ew, flag, deg);
    k_dinv<<<(N_NODES + 255) / 256, 256, 0, stream>>>(deg);
    k_gemm1<<<2048, 256, 0, stream>>>(x, W1, h1);
    k_scatter1<<<(N_EDGES * HIDDEN + 255) / 256, 256, 0, stream>>>(ei, ew, flag, deg, h1, x1);
    k_fin1_gemm2<<<(N_NODES + 255) / 256, 256, 0, stream>>>(b1, W2, deg, h1, x1, h2);
    k_scatter2<<<(N_EDGES * NCLS + 255) / 256, 256, 0, stream>>>(ei, ew, flag, deg, h2, agg2);
    k_final<<<(N_NODES + 255) / 256, 256, 0, stream>>>(agg2, h2, deg, b2, lsm);
}